// Round 7
// baseline (257.657 us; speedup 1.0000x reference)
//
#include <hip/hip_runtime.h>
#include <hip/hip_fp16.h>
#include <math.h>

#define BB 16
#define QQ 300
#define CC 256
#define NHH 8
#define SSS 8500
#define GQ 6
#define QT (QQ / GQ)          // 50
#define PRE_BLOCKS (BB * QT)  // 800
#define CONV_U4 4352000       // 16*8500*256 floats / 8 per uint4
#define CONV_BLOCKS 2834
#define CONV_THREADS (CONV_BLOCKS * 384)

// ---------------------------------------------------------------------------
// Kernel 1 (mega-dispatch): blocks [0,800) do the offsets/attn GEMM+softmax;
// blocks [800,3634) convert enc fp32 -> fp16 into d_ws. The VALU-bound GEMM
// blocks overlap with the memory-bound convert blocks across CUs (single
// stream would otherwise serialize two kernels).
// ---------------------------------------------------------------------------
__global__ __launch_bounds__(384) void prep_kernel(
    const float* __restrict__ hs,      // (B,Q,C)
    const float* __restrict__ enc,     // (B,S,256) fp32
    const float* __restrict__ refp,    // (B,Q,1,4)
    const float* __restrict__ off_k,   // (C,256)
    const float* __restrict__ off_b,   // 256
    const float* __restrict__ attn_k,  // (C,128)
    const float* __restrict__ attn_b,  // 128
    const float* __restrict__ nps,     // 16
    __half* __restrict__ enc16,        // ws: (B,S,256) fp16
    float* __restrict__ loc_t,         // ws: (B,Q,128,2) [p*8+h][xy]
    float* __restrict__ aw_t,          // ws: (B,Q,128)   [p*8+h]
    float* __restrict__ attn_out)      // d_out: (B,Q,128) [h][p]
{
    const int t = threadIdx.x;
    const int blk = blockIdx.x;

    if (blk >= PRE_BLOCKS) {
        // ---- fp32 -> fp16 conversion, grid-stride over uint4 groups ----
        const int cb = blk - PRE_BLOCKS;
        const float4* src = (const float4*)enc;
        uint4* dst = (uint4*)enc16;
        for (int i = cb * 384 + t; i < CONV_U4; i += CONV_THREADS) {
            const float4 a0 = src[2 * i];
            const float4 a1 = src[2 * i + 1];
            const __half2 h0 = __floats2half2_rn(a0.x, a0.y);
            const __half2 h1 = __floats2half2_rn(a0.z, a0.w);
            const __half2 h2 = __floats2half2_rn(a1.x, a1.y);
            const __half2 h3 = __floats2half2_rn(a1.z, a1.w);
            uint4 o;
            o.x = *(const unsigned*)&h0;
            o.y = *(const unsigned*)&h1;
            o.z = *(const unsigned*)&h2;
            o.w = *(const unsigned*)&h3;
            dst[i] = o;
        }
        return;
    }

    // ---- GEMMs + softmax (block-uniform hs -> s_load operands) ----
    const int b = blk / QT;
    const int q0 = (blk % QT) * GQ;
    const float* hsb = hs + ((size_t)b * QQ + q0) * CC;

    float acc[GQ];
#pragma unroll
    for (int g = 0; g < GQ; ++g) acc[g] = 0.f;

    if (t < 256) {
        const int h = t >> 5;
        const int p = (t >> 1) & 15;
        const int xy = t & 1;
        const float* kcol = off_k + t;
#pragma unroll 8
        for (int c = 0; c < CC; ++c) {
            const float k = kcol[c * 256];
#pragma unroll
            for (int g = 0; g < GQ; ++g)
                acc[g] = fmaf(hsb[g * CC + c], k, acc[g]);
        }
        const float scale = nps[p] * 0.5f;  // OFFSET_SCALE = 0.5
        const float bias = off_b[t];
        const int didx = ((p * 8 + h) << 1) | xy;
#pragma unroll
        for (int g = 0; g < GQ; ++g) {
            const float4 r = *(const float4*)(refp + ((size_t)b * QQ + q0 + g) * 4);
            const float center = xy ? r.y : r.x;
            const float wh     = xy ? r.w : r.z;
            loc_t[((size_t)b * QQ + q0 + g) * 256 + didx] =
                fmaf((acc[g] + bias) * scale, wh, center);
        }
    } else if (t < 384) {
        const int j = t - 256;             // 0..127 = h*16+p
        const int h = j >> 4;
        const int p = j & 15;
        const float* kcol = attn_k + j;
#pragma unroll 8
        for (int c = 0; c < CC; ++c) {
            const float k = kcol[c * 128];
#pragma unroll
            for (int g = 0; g < GQ; ++g)
                acc[g] = fmaf(hsb[g * CC + c], k, acc[g]);
        }
        const float bias = attn_b[j];
#pragma unroll
        for (int g = 0; g < GQ; ++g) {
            const float logit = acc[g] + bias;
            float m = logit;
#pragma unroll
            for (int o = 1; o < 16; o <<= 1)
                m = fmaxf(m, __shfl_xor(m, o));
            const float e = __expf(logit - m);
            float s = e;
#pragma unroll
            for (int o = 1; o < 16; o <<= 1)
                s += __shfl_xor(s, o);
            const float a = e / s;
            attn_out[((size_t)b * QQ + q0 + g) * 128 + j] = a;
            aw_t[((size_t)b * QQ + q0 + g) * 128 + p * 8 + h] = a;
        }
    }
}

// ---------------------------------------------------------------------------
// Kernel 2: bilinear sampling from the fp16 value tensor. A head-chunk per
// corner is now 64 B = ONE cache line (vs 2 for fp32): scattered beyond-L1
// traffic halves (314 -> 157 MB), doubling effective MSHR coverage of the
// L3-latency gathers, which R2..R6 showed to be the binding constraint.
// Two-phase: weights+byte-offsets once per (q,h,p) in LDS, then 8-lane
// groups gather uint2 (8 B = 4 half channels) per corner.
// ---------------------------------------------------------------------------
__global__ __launch_bounds__(256) void sample_kernel(
    const __half* __restrict__ enc16, // (B,S,256) fp16
    const float2* __restrict__ loc2,  // (B,Q,128) float2, [p*8+h]
    const float* __restrict__ aw_t,   // (B,Q,128), [p*8+h]
    float* __restrict__ out)          // (B,Q,256)
{
    __shared__ float4 sh_w[4 * 128];  // [qs][p*8+h] = {w00,w10,w01,w11}
    __shared__ int4   sh_o[4 * 128];  // [qs][p*8+h] = pixel byte offsets

    const int g = blockIdx.x;              // 0..1199
    const int xcd = g & 7;
    const int i = g >> 3;                  // 0..149
    const int b = ((i & 1) << 3) | xcd;    // batch (XCD-locked)
    const int q0 = (i >> 1) * 4;           // 0..296
    const int qbase = b * QQ + q0;

    const int t = threadIdx.x;

    // ---- Phase 1: 512 (q,h,p) tasks, 2/thread: weights + corner offsets ----
#pragma unroll
    for (int k = 0; k < 2; ++k) {
        const int tau = t + k * 256;       // qs = tau>>7, idx = tau&127
        const int idx = tau & 127;
        const int p = idx >> 3;
        const int lvl = p >> 2;
        const int Wd = 80 >> lvl;
        const float Wf = (float)Wd;
        const int st = (lvl == 0) ? 0 : (lvl == 1) ? 6400 : (lvl == 2) ? 8000 : 8400;

        const float2 l = loc2[(size_t)qbase * 128 + tau];
        const float  a = aw_t[(size_t)qbase * 128 + tau];

        const float x = l.x * Wf - 0.5f;
        const float y = l.y * Wf - 0.5f;
        const float x0f = floorf(x), y0f = floorf(y);
        const float lx = x - x0f, ly = y - y0f;
        const int x0 = (int)x0f, y0 = (int)y0f;
        const int x1 = x0 + 1, y1 = y0 + 1;

        const bool vx0 = (unsigned)x0 < (unsigned)Wd;
        const bool vx1 = (unsigned)x1 < (unsigned)Wd;
        const bool vy0 = (unsigned)y0 < (unsigned)Wd;
        const bool vy1 = (unsigned)y1 < (unsigned)Wd;

        const int x0c = min(max(x0, 0), Wd - 1);
        const int x1c = min(max(x1, 0), Wd - 1);
        const int y0c = min(max(y0, 0), Wd - 1);
        const int y1c = min(max(y1, 0), Wd - 1);

        float w00 = (1.f - lx) * (1.f - ly) * a;
        float w10 = lx * (1.f - ly) * a;
        float w01 = (1.f - lx) * ly * a;
        float w11 = lx * ly * a;
        w00 = (vx0 & vy0) ? w00 : 0.f;
        w10 = (vx1 & vy0) ? w10 : 0.f;
        w01 = (vx0 & vy1) ? w01 : 0.f;
        w11 = (vx1 & vy1) ? w11 : 0.f;

        const int r0 = (st + y0c * Wd) << 9;   // byte offsets (512 B/pixel)
        const int r1 = (st + y1c * Wd) << 9;
        sh_w[tau] = make_float4(w00, w10, w01, w11);
        sh_o[tau] = make_int4(r0 + (x0c << 9), r0 + (x1c << 9),
                              r1 + (x0c << 9), r1 + (x1c << 9));
    }
    __syncthreads();

    // ---- Phase 2: wave = query; 16 points x 4 corner uint2 gathers ----
    const int qs = t >> 6;
    const int lane = t & 63;
    const int h = lane >> 3;
    const int d4 = lane & 7;               // 4-channel chunk within head
    const char* vb = (const char*)enc16 + (size_t)b * (SSS * 512) + (h << 6) + (d4 << 3);

    float4 acc = {0.f, 0.f, 0.f, 0.f};

#pragma unroll
    for (int p = 0; p < 16; ++p) {
        const float4 w = sh_w[qs * 128 + p * 8 + h];
        const int4   o = sh_o[qs * 128 + p * 8 + h];
        const uint2 u00 = *(const uint2*)(vb + o.x);
        const uint2 u10 = *(const uint2*)(vb + o.y);
        const uint2 u01 = *(const uint2*)(vb + o.z);
        const uint2 u11 = *(const uint2*)(vb + o.w);

        const float2 a00 = __half22float2(*(const __half2*)&u00.x);
        const float2 b00 = __half22float2(*(const __half2*)&u00.y);
        const float2 a10 = __half22float2(*(const __half2*)&u10.x);
        const float2 b10 = __half22float2(*(const __half2*)&u10.y);
        const float2 a01 = __half22float2(*(const __half2*)&u01.x);
        const float2 b01 = __half22float2(*(const __half2*)&u01.y);
        const float2 a11 = __half22float2(*(const __half2*)&u11.x);
        const float2 b11 = __half22float2(*(const __half2*)&u11.y);

        acc.x = fmaf(w.x, a00.x, fmaf(w.y, a10.x, fmaf(w.z, a01.x, fmaf(w.w, a11.x, acc.x))));
        acc.y = fmaf(w.x, a00.y, fmaf(w.y, a10.y, fmaf(w.z, a01.y, fmaf(w.w, a11.y, acc.y))));
        acc.z = fmaf(w.x, b00.x, fmaf(w.y, b10.x, fmaf(w.z, b01.x, fmaf(w.w, b11.x, acc.z))));
        acc.w = fmaf(w.x, b00.y, fmaf(w.y, b10.y, fmaf(w.z, b01.y, fmaf(w.w, b11.y, acc.w))));
    }

    float* op = out + (size_t)(qbase + qs) * 256 + (h << 5) + (d4 << 2);
    *(float4*)op = acc;
}

extern "C" void kernel_launch(void* const* d_in, const int* in_sizes, int n_in,
                              void* d_out, int out_size, void* d_ws, size_t ws_size,
                              hipStream_t stream) {
    const float* hs     = (const float*)d_in[0];
    const float* enc    = (const float*)d_in[1];
    const float* refp   = (const float*)d_in[2];
    const float* off_k  = (const float*)d_in[3];
    const float* off_b  = (const float*)d_in[4];
    const float* attn_k = (const float*)d_in[5];
    const float* attn_b = (const float*)d_in[6];
    const float* nps    = (const float*)d_in[7];

    float* out      = (float*)d_out;                       // B*Q*256
    float* attn_out = out + (size_t)BB * QQ * CC;          // B*Q*128

    __half* enc16 = (__half*)d_ws;                             // 69,632,000 B
    float* loc_t  = (float*)((char*)d_ws + 69632000);          // B*Q*256 floats
    float* aw_t   = loc_t + (size_t)BB * QQ * 256;             // B*Q*128 floats

    prep_kernel<<<PRE_BLOCKS + CONV_BLOCKS, 384, 0, stream>>>(
        hs, enc, refp, off_k, off_b, attn_k, attn_b, nps,
        enc16, loc_t, aw_t, attn_out);
    sample_kernel<<<BB * (QQ / 4), 256, 0, stream>>>(
        enc16, (const float2*)loc_t, aw_t, out);
}

// Round 8
// 246.568 us; speedup vs baseline: 1.0450x; 1.0450x over previous
//
#include <hip/hip_runtime.h>
#include <math.h>

#define BB 16
#define QQ 300
#define CC 256
#define NHH 8
#define SSS 8500
#define GQ 10
#define QT (QQ / GQ) // 30

// ---------------------------------------------------------------------------
// Kernel 1: GEMMs + softmax + bilinear weight/offset precompute.
// 480 blocks x 384 threads, 10 queries/block.
//   Stage 1: t<256 -> offset col (h,p,xy) -> loc to LDS; t in [256,384) ->
//            attn logit + 16-lane softmax -> LDS + attn_out (d_out).
//   Stage 2: 1280 (q,h,p) tasks -> attn-folded bilinear weights (OOB zeroed)
//            + 4 clamped corner byte-offsets -> coalesced global ws arrays.
// Kernel 2 then never touches loc/attn/softmax — pure gather.
// ---------------------------------------------------------------------------
__global__ __launch_bounds__(384) void precompute_kernel(
    const float* __restrict__ hs,      // (B,Q,C)
    const float* __restrict__ refp,    // (B,Q,1,4)
    const float* __restrict__ off_k,   // (C,256)
    const float* __restrict__ off_b,   // 256
    const float* __restrict__ attn_k,  // (C,128)
    const float* __restrict__ attn_b,  // 128
    const float* __restrict__ nps,     // 16
    float4* __restrict__ w_arr,        // ws: (B*Q*16*8) float4 weights
    int4*  __restrict__ o_arr,         // ws: (B*Q*16*8) int4 byte-offsets
    float* __restrict__ attn_out)      // d_out: (B,Q,128) [h][p]
{
    __shared__ float sh_l[GQ * 128 * 2];  // [q][p*8+h][xy]
    __shared__ float sh_a[GQ * 128];      // [q][p*8+h]

    const int t = threadIdx.x;
    const int blk = blockIdx.x;            // 0..479
    const int b = blk / QT;
    const int q0 = (blk % QT) * GQ;
    const float* hsb = hs + ((size_t)b * QQ + q0) * CC;

    float acc[GQ];
#pragma unroll
    for (int g = 0; g < GQ; ++g) acc[g] = 0.f;

    if (t < 256) {
        const int h = t >> 5;
        const int p = (t >> 1) & 15;
        const int xy = t & 1;
        const float* kcol = off_k + t;
#pragma unroll 8
        for (int c = 0; c < CC; ++c) {
            const float k = kcol[c * 256];
#pragma unroll
            for (int g = 0; g < GQ; ++g)
                acc[g] = fmaf(hsb[g * CC + c], k, acc[g]);
        }
        const float scale = nps[p] * 0.5f;  // OFFSET_SCALE = 0.5
        const float bias = off_b[t];
        const int didx = ((p * 8 + h) << 1) | xy;
#pragma unroll
        for (int g = 0; g < GQ; ++g) {
            const float4 r = *(const float4*)(refp + ((size_t)b * QQ + q0 + g) * 4);
            const float center = xy ? r.y : r.x;
            const float wh     = xy ? r.w : r.z;
            sh_l[g * 256 + didx] = fmaf((acc[g] + bias) * scale, wh, center);
        }
    } else {
        const int j = t - 256;             // 0..127 = h*16+p
        const int h = j >> 4;
        const int p = j & 15;
        const float* kcol = attn_k + j;
#pragma unroll 8
        for (int c = 0; c < CC; ++c) {
            const float k = kcol[c * 128];
#pragma unroll
            for (int g = 0; g < GQ; ++g)
                acc[g] = fmaf(hsb[g * CC + c], k, acc[g]);
        }
        const float bias = attn_b[j];
#pragma unroll
        for (int g = 0; g < GQ; ++g) {
            const float logit = acc[g] + bias;
            float m = logit;
#pragma unroll
            for (int o = 1; o < 16; o <<= 1)
                m = fmaxf(m, __shfl_xor(m, o));
            const float e = __expf(logit - m);
            float s = e;
#pragma unroll
            for (int o = 1; o < 16; o <<= 1)
                s += __shfl_xor(s, o);
            const float a = e / s;
            attn_out[((size_t)b * QQ + q0 + g) * 128 + j] = a;
            sh_a[g * 128 + p * 8 + h] = a;
        }
    }
    __syncthreads();

    // ---- Stage 2: weights + corner offsets for 1280 tasks ----
    const size_t gbase = ((size_t)b * QQ + q0) * 128;
    for (int tau = t; tau < GQ * 128; tau += 384) {
        const int idx = tau & 127;
        const int p = idx >> 3;
        const int lvl = p >> 2;
        const int Wd = 80 >> lvl;
        const float Wf = (float)Wd;
        const int st = (lvl == 0) ? 0 : (lvl == 1) ? 6400 : (lvl == 2) ? 8000 : 8400;

        const float lxs = sh_l[tau * 2];
        const float lys = sh_l[tau * 2 + 1];
        const float a = sh_a[tau];

        const float x = lxs * Wf - 0.5f;
        const float y = lys * Wf - 0.5f;
        const float x0f = floorf(x), y0f = floorf(y);
        const float lx = x - x0f, ly = y - y0f;
        const int x0 = (int)x0f, y0 = (int)y0f;
        const int x1 = x0 + 1, y1 = y0 + 1;

        const bool vx0 = (unsigned)x0 < (unsigned)Wd;
        const bool vx1 = (unsigned)x1 < (unsigned)Wd;
        const bool vy0 = (unsigned)y0 < (unsigned)Wd;
        const bool vy1 = (unsigned)y1 < (unsigned)Wd;

        const int x0c = min(max(x0, 0), Wd - 1);
        const int x1c = min(max(x1, 0), Wd - 1);
        const int y0c = min(max(y0, 0), Wd - 1);
        const int y1c = min(max(y1, 0), Wd - 1);

        float w00 = (1.f - lx) * (1.f - ly) * a;
        float w10 = lx * (1.f - ly) * a;
        float w01 = (1.f - lx) * ly * a;
        float w11 = lx * ly * a;
        w00 = (vx0 & vy0) ? w00 : 0.f;
        w10 = (vx1 & vy0) ? w10 : 0.f;
        w01 = (vx0 & vy1) ? w01 : 0.f;
        w11 = (vx1 & vy1) ? w11 : 0.f;

        const int r0 = (st + y0c * Wd) << 10;   // bytes (1024 B / pixel)
        const int r1 = (st + y1c * Wd) << 10;
        w_arr[gbase + tau] = make_float4(w00, w10, w01, w11);
        o_arr[gbase + tau] = make_int4(r0 + (x0c << 10), r0 + (x1c << 10),
                                       r1 + (x0c << 10), r1 + (x1c << 10));
    }
}

// ---------------------------------------------------------------------------
// Kernel 2: pure gather engine. One wave per query (4800 blocks, 64 threads):
// zero LDS, zero __syncthreads. Per point: 2 broadcast loads (w,o — 8-lane
// groups read the same 16 B, L1-hit) + 4 float4 gathers + 16 FMAs. Gather
// traffic starts immediately; nothing else competes.
// ---------------------------------------------------------------------------
__global__ __launch_bounds__(64) void sample_kernel(
    const float* __restrict__ enc,     // (B,S,256)
    const float4* __restrict__ w_arr,  // (B*Q*128)
    const int4*  __restrict__ o_arr,   // (B*Q*128)
    float* __restrict__ out)           // (B,Q,256)
{
    const int g = blockIdx.x;              // 0..4799
    const int xcd = g & 7;
    const int i = g >> 3;                  // 0..599
    const int b = ((i & 1) << 3) | xcd;    // batch (XCD-locked via g%8)
    const int q = i >> 1;                  // 0..299
    const size_t mbase = ((size_t)b * QQ + q) * 128;

    const int lane = threadIdx.x;          // 0..63
    const int h = lane >> 3;
    const int d4 = (lane & 7) << 2;
    const char* vb = (const char*)(enc + (size_t)b * (SSS * 256) + h * 32 + d4);

    const float4* wp = w_arr + mbase + h;
    const int4*  op = o_arr + mbase + h;

    float4 acc = {0.f, 0.f, 0.f, 0.f};

#pragma unroll
    for (int p = 0; p < 16; ++p) {
        const float4 w = wp[p * 8];
        const int4   o = op[p * 8];
        const float4 v00 = *(const float4*)(vb + o.x);
        const float4 v10 = *(const float4*)(vb + o.y);
        const float4 v01 = *(const float4*)(vb + o.z);
        const float4 v11 = *(const float4*)(vb + o.w);
        acc.x = fmaf(w.x, v00.x, fmaf(w.y, v10.x, fmaf(w.z, v01.x, fmaf(w.w, v11.x, acc.x))));
        acc.y = fmaf(w.x, v00.y, fmaf(w.y, v10.y, fmaf(w.z, v01.y, fmaf(w.w, v11.y, acc.y))));
        acc.z = fmaf(w.x, v00.z, fmaf(w.y, v10.z, fmaf(w.z, v01.z, fmaf(w.w, v11.z, acc.z))));
        acc.w = fmaf(w.x, v00.w, fmaf(w.y, v10.w, fmaf(w.z, v01.w, fmaf(w.w, v11.w, acc.w))));
    }

    float* outp = out + ((size_t)b * QQ + q) * 256 + h * 32 + d4;
    *(float4*)outp = acc;
}

extern "C" void kernel_launch(void* const* d_in, const int* in_sizes, int n_in,
                              void* d_out, int out_size, void* d_ws, size_t ws_size,
                              hipStream_t stream) {
    const float* hs     = (const float*)d_in[0];
    const float* enc    = (const float*)d_in[1];
    const float* refp   = (const float*)d_in[2];
    const float* off_k  = (const float*)d_in[3];
    const float* off_b  = (const float*)d_in[4];
    const float* attn_k = (const float*)d_in[5];
    const float* attn_b = (const float*)d_in[6];
    const float* nps    = (const float*)d_in[7];

    float* out      = (float*)d_out;                       // B*Q*256
    float* attn_out = out + (size_t)BB * QQ * CC;          // B*Q*128

    float4* w_arr = (float4*)d_ws;                         // 614400 float4
    int4*   o_arr = (int4*)((char*)d_ws + (size_t)BB * QQ * 128 * 16);

    precompute_kernel<<<BB * QT, 384, 0, stream>>>(hs, refp, off_k, off_b,
                                                   attn_k, attn_b, nps,
                                                   w_arr, o_arr, attn_out);
    sample_kernel<<<BB * QQ, 64, 0, stream>>>(enc, w_arr, o_arr, out);
}